// Round 3
// baseline (15747.231 us; speedup 1.0000x reference)
//
#include <hip/hip_runtime.h>

// Decoder block, MI355X gfx950. ALL float tensors are float32 (per reference);
// ints int32; output float32. GEMMs use bf16 MFMA internally (convert on
// stage), f32 accumulate; residual stream kept in f32.

#define BB 16
#define SS 1024
#define DD 512
#define HH 8
#define DH 64
#define NROW (BB*SS)       // 16384

typedef unsigned short u16;
typedef __attribute__((ext_vector_type(8))) u16 u16x8;
typedef __attribute__((ext_vector_type(8))) short s16x8;
typedef __attribute__((ext_vector_type(4))) float f32x4;

__device__ __forceinline__ float b2f(u16 u) {
    return __uint_as_float(((unsigned int)u) << 16);
}
__device__ __forceinline__ u16 f2b(float f) {
    unsigned int u = __float_as_uint(f);
    return (u16)((u + 0x7FFF + ((u >> 16) & 1)) >> 16);
}
__device__ __forceinline__ s16x8 u2s8(u16x8 u) {
    union { u16x8 u; s16x8 s; } x; x.u = u; return x.s;
}
__device__ __forceinline__ f32x4 mfma16(s16x8 a, s16x8 b, f32x4 c) {
    return __builtin_amdgcn_mfma_f32_16x16x32_bf16(a, b, c, 0, 0, 0);
}
__device__ __forceinline__ float wave_sum(float v) {
    #pragma unroll
    for (int m = 1; m < 64; m <<= 1) v += __shfl_xor(v, m, 64);
    return v;
}

// ---------------- embed + LN1 : one wave per (b,s) row, f32 in/out ----------------
__global__ __launch_bounds__(256) void embed_ln_k(
    const int* __restrict__ in_ex, const int* __restrict__ in_cat,
    const int* __restrict__ in_res, const float* __restrict__ in_pos,
    const float* __restrict__ E_res, const float* __restrict__ E_ex,
    const float* __restrict__ E_cat, const float* __restrict__ g,
    const float* __restrict__ be, float* __restrict__ out)
{
    int wave = threadIdx.x >> 6, lane = threadIdx.x & 63;
    int row = blockIdx.x * 4 + wave;          // < 16384
    int res = in_res[row];
    int ex  = in_ex[row] + 10000 * res;
    int cat = in_cat[row] + 300 * res;
    int d0 = lane * 8;
    const float* pr = &E_res[(size_t)res * DD + d0];
    const float* pe = &E_ex[(size_t)ex * DD + d0];
    const float* pc = &E_cat[(size_t)cat * DD + d0];
    const float* pp = &in_pos[(size_t)row * DD + d0];
    float x[8]; float s = 0.f;
    #pragma unroll
    for (int j = 0; j < 8; j++) { x[j] = pr[j] + pe[j] + pc[j] + pp[j]; s += x[j]; }
    s = wave_sum(s);
    float mean = s * (1.0f / DD);
    float vs = 0.f;
    #pragma unroll
    for (int j = 0; j < 8; j++) { float d = x[j] - mean; vs += d * d; }
    vs = wave_sum(vs);
    float rstd = rsqrtf(vs * (1.0f / DD) + 1e-5f);
    #pragma unroll
    for (int j = 0; j < 8; j++)
        out[(size_t)row * DD + d0 + j] = (x[j] - mean) * rstd * g[d0 + j] + be[d0 + j];
}

// ---------------- generic row LayerNorm: f32 in, f32 or bf16 out ----------------
template<bool OUTB>
__global__ __launch_bounds__(256) void ln_k(
    const float* __restrict__ x, const float* __restrict__ g,
    const float* __restrict__ be, void* __restrict__ outv)
{
    int wave = threadIdx.x >> 6, lane = threadIdx.x & 63;
    int row = blockIdx.x * 4 + wave;
    int d0 = lane * 8;
    const float* px = &x[(size_t)row * DD + d0];
    float xv[8]; float s = 0.f;
    #pragma unroll
    for (int j = 0; j < 8; j++) { xv[j] = px[j]; s += xv[j]; }
    s = wave_sum(s);
    float mean = s * (1.0f / DD);
    float vs = 0.f;
    #pragma unroll
    for (int j = 0; j < 8; j++) { float d = xv[j] - mean; vs += d * d; }
    vs = wave_sum(vs);
    float rstd = rsqrtf(vs * (1.0f / DD) + 1e-5f);
    #pragma unroll
    for (int j = 0; j < 8; j++) {
        float v = (xv[j] - mean) * rstd * g[d0 + j] + be[d0 + j];
        if (OUTB) ((u16*)outv)[(size_t)row * DD + d0 + j] = f2b(v);
        else      ((float*)outv)[(size_t)row * DD + d0 + j] = v;
    }
}

// ---------------- weight transpose + cast: f32 W[k][n] -> bf16 Wt[n][k] ----------------
__global__ __launch_bounds__(256) void transpose_k(const float* __restrict__ src, u16* __restrict__ dst)
{
    int idx = blockIdx.x * 256 + threadIdx.x;   // 262144 total
    int n = idx & 511, k = idx >> 9;
    dst[n * 512 + k] = f2b(src[k * 512 + n]);
}

// ---------------- MFMA GEMM: C(M,512) = A(M,512) @ W(512,512) + bias [relu] [+resid] ----------------
// A: f32 or bf16 (AF32). Wt: bf16 transposed (N,K). bias/resid: f32. C: f32 or bf16 (OUTB).
template<bool AF32, bool RELU, bool RES, bool OUTB>
__global__ __launch_bounds__(256) void gemm_k(
    const void* __restrict__ Av, const u16* __restrict__ Wt,
    const float* __restrict__ bias, const float* __restrict__ resid,
    void* __restrict__ Cv, int M, int K)
{
    const int N = 512;
    __shared__ __align__(16) u16 As[128 * 40];
    __shared__ __align__(16) u16 Bs[128 * 40];
    int tid = threadIdx.x;
    int wave = tid >> 6, lane = tid & 63;
    int quad = lane >> 4, l16 = lane & 15;
    int m0 = blockIdx.y * 128, n0 = blockIdx.x * 128;
    int wm = (wave >> 1) * 64, wn = (wave & 1) * 64;
    int r = tid >> 1, cg = (tid & 1) * 16;     // staging: row r, 16-col group
    f32x4 acc[4][4];
    #pragma unroll
    for (int i = 0; i < 4; i++)
        #pragma unroll
        for (int j = 0; j < 4; j++)
            #pragma unroll
            for (int rr = 0; rr < 4; rr++) acc[i][j][rr] = 0.f;

    for (int k0 = 0; k0 < K; k0 += 32) {
        __syncthreads();
        if (AF32) {
            const float* src = &((const float*)Av)[(size_t)(m0 + r) * K + k0 + cg];
            u16x8 lo, hi;
            #pragma unroll
            for (int j = 0; j < 8; j++) { lo[j] = f2b(src[j]); hi[j] = f2b(src[j + 8]); }
            *(u16x8*)&As[r * 40 + cg] = lo;
            *(u16x8*)&As[r * 40 + cg + 8] = hi;
        } else {
            const u16* src = &((const u16*)Av)[(size_t)(m0 + r) * K + k0 + cg];
            *(u16x8*)&As[r * 40 + cg] = *(const u16x8*)&src[0];
            *(u16x8*)&As[r * 40 + cg + 8] = *(const u16x8*)&src[8];
        }
        {
            const u16* src = &Wt[(size_t)(n0 + r) * K + k0 + cg];
            *(u16x8*)&Bs[r * 40 + cg] = *(const u16x8*)&src[0];
            *(u16x8*)&Bs[r * 40 + cg + 8] = *(const u16x8*)&src[8];
        }
        __syncthreads();
        s16x8 af[4], bfr[4];
        #pragma unroll
        for (int i = 0; i < 4; i++)
            af[i] = u2s8(*(const u16x8*)&As[(wm + i * 16 + l16) * 40 + quad * 8]);
        #pragma unroll
        for (int j = 0; j < 4; j++)
            bfr[j] = u2s8(*(const u16x8*)&Bs[(wn + j * 16 + l16) * 40 + quad * 8]);
        #pragma unroll
        for (int i = 0; i < 4; i++)
            #pragma unroll
            for (int j = 0; j < 4; j++)
                acc[i][j] = mfma16(af[i], bfr[j], acc[i][j]);
    }

    #pragma unroll
    for (int j = 0; j < 4; j++) {
        int col = n0 + wn + j * 16 + l16;
        float bv = bias[col];
        #pragma unroll
        for (int i = 0; i < 4; i++) {
            int rowb = m0 + wm + i * 16 + quad * 4;
            #pragma unroll
            for (int rr = 0; rr < 4; rr++) {
                float v = acc[i][j][rr] + bv;
                if (RELU) v = fmaxf(v, 0.f);
                if (RES) v += resid[(size_t)(rowb + rr) * N + col];
                if (OUTB) ((u16*)Cv)[(size_t)(rowb + rr) * N + col] = f2b(v);
                else      ((float*)Cv)[(size_t)(rowb + rr) * N + col] = v;
            }
        }
    }
}

// ---------------- naive pyramid attention: one wave per (b,h,q), bf16 in/out ----------------
__global__ __launch_bounds__(64) void attn_simple_k(
    const u16* __restrict__ Q, const u16* __restrict__ K, const u16* __restrict__ V,
    u16* __restrict__ O)
{
    int d = threadIdx.x;               // 0..63 = dh index
    int q = blockIdx.x, h = blockIdx.y, b = blockIdx.z;
    size_t base = ((size_t)(b * SS)) * DD + h * DH + d;
    float qv = b2f(Q[((size_t)(b * SS + q)) * DD + h * DH + d]);
    float m = -INFINITY, l = 0.f, o = 0.f;
    for (int lv = 0; lv < 3; lv++) {
        int f = 1 << lv;
        int jmax = (q + 1) / f - 1;    // causal: q >= (j+1)*f - 1
        float inv = 1.0f / (float)f;
        for (int j = 0; j <= jmax; j++) {
            float ks = 0.f, vs = 0.f;
            for (int i = 0; i < f; i++) {
                size_t off = base + (size_t)(j * f + i) * DD;
                ks += b2f(K[off]);
                vs += b2f(V[off]);
            }
            ks *= inv; vs *= inv;
            float s = qv * ks;
            #pragma unroll
            for (int mm = 1; mm < 64; mm <<= 1) s += __shfl_xor(s, mm, 64);
            s *= 0.125f;               // 1/sqrt(64)
            float nm = fmaxf(m, s);
            float al = __expf(m - nm);
            float p  = __expf(s - nm);
            l = l * al + p;
            o = o * al + p * vs;
            m = nm;
        }
    }
    O[((size_t)(b * SS + q)) * DD + h * DH + d] = f2b(o / l);
}

extern "C" void kernel_launch(void* const* d_in, const int* in_sizes, int n_in,
                              void* d_out, int out_size, void* d_ws, size_t ws_size,
                              hipStream_t stream)
{
    (void)in_sizes; (void)n_in; (void)out_size; (void)ws_size;
    const int* in_ex  = (const int*)d_in[0];
    const int* in_cat = (const int*)d_in[1];
    const int* in_res = (const int*)d_in[2];
    const float* in_pos = (const float*)d_in[3];
    const float* en_out = (const float*)d_in[4];
    const float* E_res  = (const float*)d_in[5];
    const float* E_ex   = (const float*)d_in[6];
    const float* E_cat  = (const float*)d_in[7];
    const float* g1 = (const float*)d_in[8],  *be1 = (const float*)d_in[9];
    const float* g2 = (const float*)d_in[10], *be2 = (const float*)d_in[11];
    const float* g3 = (const float*)d_in[12], *be3 = (const float*)d_in[13];
    const float* Wq1 = (const float*)d_in[14], *bq1 = (const float*)d_in[15];
    const float* Wk1 = (const float*)d_in[16], *bk1 = (const float*)d_in[17];
    const float* Wv1 = (const float*)d_in[18], *bv1 = (const float*)d_in[19];
    const float* Wo1 = (const float*)d_in[20], *bo1 = (const float*)d_in[21];
    const float* Wq2 = (const float*)d_in[22], *bq2 = (const float*)d_in[23];
    const float* Wk2 = (const float*)d_in[24], *bk2 = (const float*)d_in[25];
    const float* Wv2 = (const float*)d_in[26], *bv2 = (const float*)d_in[27];
    const float* Wo2 = (const float*)d_in[28], *bo2 = (const float*)d_in[29];
    const float* fW1 = (const float*)d_in[30], *fb1 = (const float*)d_in[31];
    const float* fW2 = (const float*)d_in[32], *fb2 = (const float*)d_in[33];

    char* ws = (char*)d_ws;
    const size_t U = (size_t)NROW * DD * 2;     // 16.78 MB (one bf16 activation)
    float* x1 = (float*)(ws);                   // f32, 2U   [phase4+: x3]
    u16* qb = (u16*)(ws + 2 * U);               // bf16, 1U
    u16* kb = (u16*)(ws + 3 * U);               // bf16, 1U  [phase5: x4 f32 spans 3U..5U]
    u16* vb = (u16*)(ws + 4 * U);               // bf16, 1U
    u16* hb = (u16*)(ws + 5 * U);               // bf16, 1U  [phase5: ff1]
    u16* en = (u16*)(ws + 6 * U);               // bf16, 1U
    u16* wt = (u16*)(ws + 7 * U);               // 10 x 512KB bf16 transposed weights
    // total ws use: 7U + 5.24 MB ~= 122.7 MB
    float* x2 = (float*)d_out;                  // d_out doubles as x2 scratch (fully overwritten at end)

    const float* wsrc[10] = {Wq1, Wk1, Wv1, Wo1, Wq2, Wk2, Wv2, Wo2, fW1, fW2};
    for (int i = 0; i < 10; i++)
        transpose_k<<<1024, 256, 0, stream>>>(wsrc[i], wt + (size_t)i * 262144);
    u16* tWq1 = wt,            *tWk1 = wt + 262144,   *tWv1 = wt + 2*262144, *tWo1 = wt + 3*262144;
    u16* tWq2 = wt + 4*262144, *tWk2 = wt + 5*262144, *tWv2 = wt + 6*262144, *tWo2 = wt + 7*262144;
    u16* tF1  = wt + 8*262144, *tF2  = wt + 9*262144;

    dim3 ggrid(4, 128);
    dim3 agrid(SS, HH, BB);

    // phase 2: x1 = LN1(embed sum)   (f32)
    embed_ln_k<<<4096, 256, 0, stream>>>(in_ex, in_cat, in_res, in_pos,
                                         E_res, E_ex, E_cat, g1, be1, x1);

    // phase 3: self-attention; x2 = x1 + attn(x1) @ Wo1
    gemm_k<true,false,false,true><<<ggrid, 256, 0, stream>>>(x1, tWq1, bq1, nullptr, qb, NROW, 512);
    gemm_k<true,false,false,true><<<ggrid, 256, 0, stream>>>(x1, tWk1, bk1, nullptr, kb, NROW, 512);
    gemm_k<true,false,false,true><<<ggrid, 256, 0, stream>>>(x1, tWv1, bv1, nullptr, vb, NROW, 512);
    attn_simple_k<<<agrid, 64, 0, stream>>>(qb, kb, vb, hb);
    gemm_k<false,false,true,false><<<ggrid, 256, 0, stream>>>(hb, tWo1, bo1, x1, x2, NROW, 512);

    // phase 4: cross-attention; x3 = x2 + attn(q=x2, kv=en) @ Wo2
    ln_k<true><<<4096, 256, 0, stream>>>(en_out, g2, be2, en);
    gemm_k<true,false,false,true><<<ggrid, 256, 0, stream>>>(x2, tWq2, bq2, nullptr, qb, NROW, 512);
    gemm_k<false,false,false,true><<<ggrid, 256, 0, stream>>>(en, tWk2, bk2, nullptr, kb, NROW, 512);
    gemm_k<false,false,false,true><<<ggrid, 256, 0, stream>>>(en, tWv2, bv2, nullptr, vb, NROW, 512);
    attn_simple_k<<<agrid, 64, 0, stream>>>(qb, kb, vb, hb);
    float* x3 = x1;   // x1 dead after O1-residual consumed; reuse slot
    gemm_k<false,false,true,false><<<ggrid, 256, 0, stream>>>(hb, tWo2, bo2, x2, x3, NROW, 512);

    // phase 5: x4 = LN3(x3); out = x4 + relu(x4@fW1+fb1)@fW2+fb2
    float* x4 = (float*)(ws + 3 * U);   // kb+vb slots (dead)
    u16* ff1 = hb;                      // hb slot (dead)
    ln_k<false><<<4096, 256, 0, stream>>>(x3, g3, be3, x4);
    gemm_k<true,true,false,true><<<ggrid, 256, 0, stream>>>(x4, tF1, fb1, nullptr, ff1, NROW, 512);
    gemm_k<false,false,true,false><<<ggrid, 256, 0, stream>>>(ff1, tF2, fb2, x4, (float*)d_out, NROW, 512);
}

// Round 4
// 1506.367 us; speedup vs baseline: 10.4538x; 10.4538x over previous
//
#include <hip/hip_runtime.h>

// Decoder block, MI355X gfx950. ALL float tensors f32 (per reference); ints
// int32; output f32. GEMMs + attention use bf16 MFMA internally, f32
// accumulate; residual stream kept in f32.

#define BB 16
#define SS 1024
#define DD 512
#define HH 8
#define DH 64
#define KTOT 1792          // 1024 + 512 + 256 pyramid keys
#define NROW (BB*SS)       // 16384

typedef unsigned short u16;
typedef __attribute__((ext_vector_type(8))) u16 u16x8;
typedef __attribute__((ext_vector_type(8))) short s16x8;
typedef __attribute__((ext_vector_type(4))) float f32x4;

__device__ __forceinline__ float b2f(u16 u) {
    return __uint_as_float(((unsigned int)u) << 16);
}
__device__ __forceinline__ u16 f2b(float f) {
    unsigned int u = __float_as_uint(f);
    return (u16)((u + 0x7FFF + ((u >> 16) & 1)) >> 16);
}
__device__ __forceinline__ s16x8 u2s8(u16x8 u) {
    union { u16x8 u; s16x8 s; } x; x.u = u; return x.s;
}
__device__ __forceinline__ f32x4 mfma16(s16x8 a, s16x8 b, f32x4 c) {
    return __builtin_amdgcn_mfma_f32_16x16x32_bf16(a, b, c, 0, 0, 0);
}
__device__ __forceinline__ float wave_sum(float v) {
    #pragma unroll
    for (int m = 1; m < 64; m <<= 1) v += __shfl_xor(v, m, 64);
    return v;
}

// ---------------- embed + LN1 : one wave per (b,s) row, f32 in/out ----------------
__global__ __launch_bounds__(256) void embed_ln_k(
    const int* __restrict__ in_ex, const int* __restrict__ in_cat,
    const int* __restrict__ in_res, const float* __restrict__ in_pos,
    const float* __restrict__ E_res, const float* __restrict__ E_ex,
    const float* __restrict__ E_cat, const float* __restrict__ g,
    const float* __restrict__ be, float* __restrict__ out)
{
    int wave = threadIdx.x >> 6, lane = threadIdx.x & 63;
    int row = blockIdx.x * 4 + wave;          // < 16384
    int res = in_res[row];
    int ex  = in_ex[row] + 10000 * res;
    int cat = in_cat[row] + 300 * res;
    int d0 = lane * 8;
    const float* pr = &E_res[(size_t)res * DD + d0];
    const float* pe = &E_ex[(size_t)ex * DD + d0];
    const float* pc = &E_cat[(size_t)cat * DD + d0];
    const float* pp = &in_pos[(size_t)row * DD + d0];
    float x[8]; float s = 0.f;
    #pragma unroll
    for (int j = 0; j < 8; j++) { x[j] = pr[j] + pe[j] + pc[j] + pp[j]; s += x[j]; }
    s = wave_sum(s);
    float mean = s * (1.0f / DD);
    float vs = 0.f;
    #pragma unroll
    for (int j = 0; j < 8; j++) { float d = x[j] - mean; vs += d * d; }
    vs = wave_sum(vs);
    float rstd = rsqrtf(vs * (1.0f / DD) + 1e-5f);
    #pragma unroll
    for (int j = 0; j < 8; j++)
        out[(size_t)row * DD + d0 + j] = (x[j] - mean) * rstd * g[d0 + j] + be[d0 + j];
}

// ---------------- generic row LayerNorm: f32 in, f32 or bf16 out ----------------
template<bool OUTB>
__global__ __launch_bounds__(256) void ln_k(
    const float* __restrict__ x, const float* __restrict__ g,
    const float* __restrict__ be, void* __restrict__ outv)
{
    int wave = threadIdx.x >> 6, lane = threadIdx.x & 63;
    int row = blockIdx.x * 4 + wave;
    int d0 = lane * 8;
    const float* px = &x[(size_t)row * DD + d0];
    float xv[8]; float s = 0.f;
    #pragma unroll
    for (int j = 0; j < 8; j++) { xv[j] = px[j]; s += xv[j]; }
    s = wave_sum(s);
    float mean = s * (1.0f / DD);
    float vs = 0.f;
    #pragma unroll
    for (int j = 0; j < 8; j++) { float d = xv[j] - mean; vs += d * d; }
    vs = wave_sum(vs);
    float rstd = rsqrtf(vs * (1.0f / DD) + 1e-5f);
    #pragma unroll
    for (int j = 0; j < 8; j++) {
        float v = (xv[j] - mean) * rstd * g[d0 + j] + be[d0 + j];
        if (OUTB) ((u16*)outv)[(size_t)row * DD + d0 + j] = f2b(v);
        else      ((float*)outv)[(size_t)row * DD + d0 + j] = v;
    }
}

// ---------------- weight transpose + cast: f32 W[k][n] -> bf16 Wt[n][k] ----------------
__global__ __launch_bounds__(256) void transpose_k(const float* __restrict__ src, u16* __restrict__ dst)
{
    int idx = blockIdx.x * 256 + threadIdx.x;   // 262144 total
    int n = idx & 511, k = idx >> 9;
    dst[n * 512 + k] = f2b(src[k * 512 + n]);
}

// ---------------- K pyramid pool levels 1-2: (B,S,D) -> (B,H,768,64) ----------------
__global__ __launch_bounds__(256) void pool_k12_k(const u16* __restrict__ Kp, u16* __restrict__ KP12)
{
    int idx = blockIdx.x * 256 + threadIdx.x;   // 16*8*768*64 = 6291456
    int d = idx & 63;
    int t = idx >> 6;
    int k12 = t % 768;
    int bh = t / 768;
    int h = bh & 7, b = bh >> 3;
    int s0, f;
    if (k12 < 512) { s0 = 2 * k12; f = 2; } else { s0 = 4 * (k12 - 512); f = 4; }
    float acc = 0.f;
    for (int i = 0; i < f; i++)
        acc += b2f(Kp[((size_t)(b * SS + s0 + i)) * DD + h * DH + d]);
    KP12[idx] = f2b(acc * (1.0f / (float)f));
}

// ---------------- V pyramid pool, transposed: (B,S,D) -> (B,H,64,1792) ----------------
__global__ __launch_bounds__(256) void pool_vt_k(const u16* __restrict__ Vp, u16* __restrict__ VPt)
{
    int key = blockIdx.x * 256 + threadIdx.x;   // 0..1791
    int d = blockIdx.y;                         // 0..63
    int bh = blockIdx.z;                        // 0..127
    int h = bh & 7, b = bh >> 3;
    int s0, f;
    if (key < 1024)      { s0 = key; f = 1; }
    else if (key < 1536) { s0 = 2 * (key - 1024); f = 2; }
    else                 { s0 = 4 * (key - 1536); f = 4; }
    float acc = 0.f;
    for (int i = 0; i < f; i++)
        acc += b2f(Vp[((size_t)(b * SS + s0 + i)) * DD + h * DH + d]);
    VPt[((size_t)bh * DH + d) * KTOT + key] = f2b(acc * (1.0f / (float)f));
}

// ---------------- MFMA GEMM: C(M,512) = A(M,512) @ W(512,512) + bias [relu] [+resid] ----------------
template<bool AF32, bool RELU, bool RES, bool OUTB>
__global__ __launch_bounds__(256) void gemm_k(
    const void* __restrict__ Av, const u16* __restrict__ Wt,
    const float* __restrict__ bias, const float* __restrict__ resid,
    void* __restrict__ Cv, int M, int K)
{
    const int N = 512;
    __shared__ __align__(16) u16 As[128 * 40];
    __shared__ __align__(16) u16 Bs[128 * 40];
    int tid = threadIdx.x;
    int wave = tid >> 6, lane = tid & 63;
    int quad = lane >> 4, l16 = lane & 15;
    int m0 = blockIdx.y * 128, n0 = blockIdx.x * 128;
    int wm = (wave >> 1) * 64, wn = (wave & 1) * 64;
    int r = tid >> 1, cg = (tid & 1) * 16;
    f32x4 acc[4][4];
    #pragma unroll
    for (int i = 0; i < 4; i++)
        #pragma unroll
        for (int j = 0; j < 4; j++)
            #pragma unroll
            for (int rr = 0; rr < 4; rr++) acc[i][j][rr] = 0.f;

    for (int k0 = 0; k0 < K; k0 += 32) {
        __syncthreads();
        if (AF32) {
            const float* src = &((const float*)Av)[(size_t)(m0 + r) * K + k0 + cg];
            u16x8 lo, hi;
            #pragma unroll
            for (int j = 0; j < 8; j++) { lo[j] = f2b(src[j]); hi[j] = f2b(src[j + 8]); }
            *(u16x8*)&As[r * 40 + cg] = lo;
            *(u16x8*)&As[r * 40 + cg + 8] = hi;
        } else {
            const u16* src = &((const u16*)Av)[(size_t)(m0 + r) * K + k0 + cg];
            *(u16x8*)&As[r * 40 + cg] = *(const u16x8*)&src[0];
            *(u16x8*)&As[r * 40 + cg + 8] = *(const u16x8*)&src[8];
        }
        {
            const u16* src = &Wt[(size_t)(n0 + r) * K + k0 + cg];
            *(u16x8*)&Bs[r * 40 + cg] = *(const u16x8*)&src[0];
            *(u16x8*)&Bs[r * 40 + cg + 8] = *(const u16x8*)&src[8];
        }
        __syncthreads();
        s16x8 af[4], bfr[4];
        #pragma unroll
        for (int i = 0; i < 4; i++)
            af[i] = u2s8(*(const u16x8*)&As[(wm + i * 16 + l16) * 40 + quad * 8]);
        #pragma unroll
        for (int j = 0; j < 4; j++)
            bfr[j] = u2s8(*(const u16x8*)&Bs[(wn + j * 16 + l16) * 40 + quad * 8]);
        #pragma unroll
        for (int i = 0; i < 4; i++)
            #pragma unroll
            for (int j = 0; j < 4; j++)
                acc[i][j] = mfma16(af[i], bfr[j], acc[i][j]);
    }

    #pragma unroll
    for (int j = 0; j < 4; j++) {
        int col = n0 + wn + j * 16 + l16;
        float bv = bias[col];
        #pragma unroll
        for (int i = 0; i < 4; i++) {
            int rowb = m0 + wm + i * 16 + quad * 4;
            #pragma unroll
            for (int rr = 0; rr < 4; rr++) {
                float v = acc[i][j][rr] + bv;
                if (RELU) v = fmaxf(v, 0.f);
                if (RES) v += resid[(size_t)(rowb + rr) * N + col];
                if (OUTB) ((u16*)Cv)[(size_t)(rowb + rr) * N + col] = f2b(v);
                else      ((float*)Cv)[(size_t)(rowb + rr) * N + col] = v;
            }
        }
    }
}

// ---------------- MFMA flash pyramid attention ----------------
// grid (16 qtiles, H, B) x 256thr = 4 waves; each wave owns 16 queries.
// K level 0 read directly from the (B,S,D) K projection; levels 1-2 from
// KP12 (B,H,768,64); V from transposed pooled VPt (B,H,64,1792).
__global__ __launch_bounds__(256) void attn_k(
    const u16* __restrict__ Qp, const u16* __restrict__ Klin,
    const u16* __restrict__ KP12, const u16* __restrict__ VPt,
    u16* __restrict__ Hout)
{
    __shared__ __align__(16) u16 Pl[4][16 * 40];
    int tid = threadIdx.x;
    int wave = tid >> 6, lane = tid & 63;
    int quad = lane >> 4, l16 = lane & 15;
    int qt = blockIdx.x, h = blockIdx.y, b = blockIdx.z;
    int q0 = qt * 64 + wave * 16;
    int qmax = q0 + 15;

    const u16* qrow = Qp + ((size_t)(b * SS + q0 + l16)) * DD + h * DH;
    s16x8 qa0 = u2s8(*(const u16x8*)&qrow[quad * 8]);
    s16x8 qa1 = u2s8(*(const u16x8*)&qrow[32 + quad * 8]);
    const u16* K0  = Klin + ((size_t)(b * SS)) * DD + h * DH;     // + key*DD
    const u16* K12 = KP12 + ((size_t)(b * HH + h)) * 768 * DH;    // + (key-1024)*DH
    const u16* Vt  = VPt  + ((size_t)(b * HH + h)) * DH * KTOT;   // + d*KTOT + key

    f32x4 o[4];
    #pragma unroll
    for (int j = 0; j < 4; j++)
        #pragma unroll
        for (int r = 0; r < 4; r++) o[j][r] = 0.f;
    float mrow[4] = {-INFINITY, -INFINITY, -INFINITY, -INFINITY};
    float lrow[4] = {0.f, 0.f, 0.f, 0.f};

    u16* Pw = &Pl[wave][0];
    const int lev_start[3] = {0, 32, 48};   // in 32-key chunks
    const int lev_n[3]     = {32, 16, 8};

    for (int lv = 0; lv < 3; lv++) {
        for (int cc = 0; cc < lev_n[lv]; cc++) {
            int kbase = (lev_start[lv] + cc) * 32;
            int minend;                       // pooled-block end of first key in chunk
            if (lv == 0)      minend = kbase;
            else if (lv == 1) minend = 2 * (kbase - 1024) + 1;
            else              minend = 4 * (kbase - 1536) + 3;
            if (minend > qmax) break;         // rest of level fully masked for this wave

            // QK^T: two 16-key halves
            f32x4 s[2];
            #pragma unroll
            for (int t = 0; t < 2; t++) {
                int kb0 = kbase + t * 16;
                const u16* kr = (lv == 0) ? &K0[(size_t)(kb0 + l16) * DD]
                                          : &K12[(size_t)(kb0 - 1024 + l16) * DH];
                s16x8 kf0 = u2s8(*(const u16x8*)&kr[quad * 8]);
                s16x8 kf1 = u2s8(*(const u16x8*)&kr[32 + quad * 8]);
                f32x4 z;
                #pragma unroll
                for (int r = 0; r < 4; r++) z[r] = 0.f;
                z = mfma16(qa0, kf0, z);
                z = mfma16(qa1, kf1, z);
                int key = kb0 + l16;
                int e = (lv == 0) ? key
                      : (lv == 1) ? (2 * (key - 1024) + 1)
                                  : (4 * (key - 1536) + 3);
                #pragma unroll
                for (int r = 0; r < 4; r++) {
                    int q = q0 + quad * 4 + r;
                    s[t][r] = (q >= e) ? z[r] * 0.125f : -1e30f;
                }
            }

            // online softmax (row q lives in one quad's 16 lanes)
            float pr[2][4];
            #pragma unroll
            for (int r = 0; r < 4; r++) {
                float mx = fmaxf(s[0][r], s[1][r]);
                #pragma unroll
                for (int m = 1; m < 16; m <<= 1) mx = fmaxf(mx, __shfl_xor(mx, m, 64));
                float newm = fmaxf(mrow[r], mx);
                float alpha = __expf(mrow[r] - newm);
                float p0 = __expf(s[0][r] - newm);
                float p1 = __expf(s[1][r] - newm);
                float ps = p0 + p1;
                #pragma unroll
                for (int m = 1; m < 16; m <<= 1) ps += __shfl_xor(ps, m, 64);
                lrow[r] = lrow[r] * alpha + ps;
                mrow[r] = newm;
                #pragma unroll
                for (int j = 0; j < 4; j++) o[j][r] *= alpha;
                pr[0][r] = p0; pr[1][r] = p1;
            }

            // P: C-layout -> LDS -> A-layout
            #pragma unroll
            for (int t = 0; t < 2; t++)
                #pragma unroll
                for (int r = 0; r < 4; r++)
                    Pw[(quad * 4 + r) * 40 + t * 16 + l16] = f2b(pr[t][r]);
            asm volatile("s_waitcnt lgkmcnt(0)" ::: "memory");
            s16x8 pf = u2s8(*(const u16x8*)&Pw[l16 * 40 + quad * 8]);

            // PV: 4 tiles of 16 dh columns, vector B-fragment loads from Vt
            #pragma unroll
            for (int j = 0; j < 4; j++) {
                const u16* vr = &Vt[(size_t)(j * 16 + l16) * KTOT + kbase + quad * 8];
                o[j] = mfma16(pf, u2s8(*(const u16x8*)vr), o[j]);
            }
        }
    }

    #pragma unroll
    for (int r = 0; r < 4; r++) {
        int q = q0 + quad * 4 + r;
        float invl = 1.0f / lrow[r];
        #pragma unroll
        for (int j = 0; j < 4; j++)
            Hout[((size_t)(b * SS + q)) * DD + h * DH + j * 16 + l16] = f2b(o[j][r] * invl);
    }
}

extern "C" void kernel_launch(void* const* d_in, const int* in_sizes, int n_in,
                              void* d_out, int out_size, void* d_ws, size_t ws_size,
                              hipStream_t stream)
{
    (void)in_sizes; (void)n_in; (void)out_size; (void)ws_size;
    const int* in_ex  = (const int*)d_in[0];
    const int* in_cat = (const int*)d_in[1];
    const int* in_res = (const int*)d_in[2];
    const float* in_pos = (const float*)d_in[3];
    const float* en_out = (const float*)d_in[4];
    const float* E_res  = (const float*)d_in[5];
    const float* E_ex   = (const float*)d_in[6];
    const float* E_cat  = (const float*)d_in[7];
    const float* g1 = (const float*)d_in[8],  *be1 = (const float*)d_in[9];
    const float* g2 = (const float*)d_in[10], *be2 = (const float*)d_in[11];
    const float* g3 = (const float*)d_in[12], *be3 = (const float*)d_in[13];
    const float* Wq1 = (const float*)d_in[14], *bq1 = (const float*)d_in[15];
    const float* Wk1 = (const float*)d_in[16], *bk1 = (const float*)d_in[17];
    const float* Wv1 = (const float*)d_in[18], *bv1 = (const float*)d_in[19];
    const float* Wo1 = (const float*)d_in[20], *bo1 = (const float*)d_in[21];
    const float* Wq2 = (const float*)d_in[22], *bq2 = (const float*)d_in[23];
    const float* Wk2 = (const float*)d_in[24], *bk2 = (const float*)d_in[25];
    const float* Wv2 = (const float*)d_in[26], *bv2 = (const float*)d_in[27];
    const float* Wo2 = (const float*)d_in[28], *bo2 = (const float*)d_in[29];
    const float* fW1 = (const float*)d_in[30], *fb1 = (const float*)d_in[31];
    const float* fW2 = (const float*)d_in[32], *fb2 = (const float*)d_in[33];

    char* ws = (char*)d_ws;
    const size_t U = (size_t)NROW * DD * 2;        // 16.78 MB
    float* x1 = (float*)(ws);                      // 2U f32  [ph4: en bf16 in 1st U; then x3 f32]
    u16* qb   = (u16*)(ws + 2 * U);                // 1U
    u16* kb   = (u16*)(ws + 3 * U);                // 1U
    u16* vb   = (u16*)(ws + 4 * U);                // 1U
    u16* hb   = (u16*)(ws + 5 * U);                // 1U  [ph5: ff1]
    u16* kp12 = (u16*)(ws + 6 * U);                // 0.75U (B,H,768,64)
    u16* vpt  = (u16*)(ws + 6 * U + 3 * U / 4);    // 1.75U (B,H,64,1792)
    u16* wt   = (u16*)(ws + 8 * U + U / 2);        // 10 x 512KB bf16 transposed weights
    // peak ws use: 8.5U + 5.24MB ~= 148 MB
    float* x2 = (float*)d_out;                     // d_out doubles as x2 (fully overwritten at end)
    u16* en = (u16*)(ws);                          // phase-4 alias of dead x1 slot
    float* x3 = x1;                                // phase-4 output slot
    float* x4 = (float*)(ws + 6 * U);              // phase-5 alias over kp12+vpt (dead)
    u16* ff1 = hb;                                 // phase-5 alias

    const float* wsrc[10] = {Wq1, Wk1, Wv1, Wo1, Wq2, Wk2, Wv2, Wo2, fW1, fW2};
    for (int i = 0; i < 10; i++)
        transpose_k<<<1024, 256, 0, stream>>>(wsrc[i], wt + (size_t)i * 262144);
    u16* tWq1 = wt,            *tWk1 = wt + 262144,   *tWv1 = wt + 2*262144, *tWo1 = wt + 3*262144;
    u16* tWq2 = wt + 4*262144, *tWk2 = wt + 5*262144, *tWv2 = wt + 6*262144, *tWo2 = wt + 7*262144;
    u16* tF1  = wt + 8*262144, *tF2  = wt + 9*262144;

    dim3 ggrid(4, 128);
    dim3 agrid(16, HH, BB);
    dim3 vtgrid(7, 64, 128);

    // phase 2: x1 = LN1(embed sum)   (f32)
    embed_ln_k<<<4096, 256, 0, stream>>>(in_ex, in_cat, in_res, in_pos,
                                         E_res, E_ex, E_cat, g1, be1, x1);

    // phase 3: self-attention; x2 = x1 + attn(x1) @ Wo1
    gemm_k<true,false,false,true><<<ggrid, 256, 0, stream>>>(x1, tWq1, bq1, nullptr, qb, NROW, 512);
    gemm_k<true,false,false,true><<<ggrid, 256, 0, stream>>>(x1, tWk1, bk1, nullptr, kb, NROW, 512);
    gemm_k<true,false,false,true><<<ggrid, 256, 0, stream>>>(x1, tWv1, bv1, nullptr, vb, NROW, 512);
    pool_k12_k<<<24576, 256, 0, stream>>>(kb, kp12);
    pool_vt_k<<<vtgrid, 256, 0, stream>>>(vb, vpt);
    attn_k<<<agrid, 256, 0, stream>>>(qb, kb, kp12, vpt, hb);
    gemm_k<false,false,true,false><<<ggrid, 256, 0, stream>>>(hb, tWo1, bo1, x1, x2, NROW, 512);

    // phase 4: cross-attention; x3 = x2 + attn(q=x2, kv=en) @ Wo2
    ln_k<true><<<4096, 256, 0, stream>>>(en_out, g2, be2, en);
    gemm_k<true,false,false,true><<<ggrid, 256, 0, stream>>>(x2, tWq2, bq2, nullptr, qb, NROW, 512);
    gemm_k<false,false,false,true><<<ggrid, 256, 0, stream>>>(en, tWk2, bk2, nullptr, kb, NROW, 512);
    gemm_k<false,false,false,true><<<ggrid, 256, 0, stream>>>(en, tWv2, bv2, nullptr, vb, NROW, 512);
    pool_k12_k<<<24576, 256, 0, stream>>>(kb, kp12);
    pool_vt_k<<<vtgrid, 256, 0, stream>>>(vb, vpt);
    attn_k<<<agrid, 256, 0, stream>>>(qb, kb, kp12, vpt, hb);
    gemm_k<false,false,true,false><<<ggrid, 256, 0, stream>>>(hb, tWo2, bo2, x2, x3, NROW, 512);

    // phase 5: x4 = LN3(x3); out = x4 + relu(x4@fW1+fb1)@fW2+fb2
    ln_k<false><<<4096, 256, 0, stream>>>(x3, g3, be3, x4);
    gemm_k<true,true,false,true><<<ggrid, 256, 0, stream>>>(x4, tF1, fb1, nullptr, ff1, NROW, 512);
    gemm_k<false,false,true,false><<<ggrid, 256, 0, stream>>>(ff1, tF2, fb2, x4, (float*)d_out, NROW, 512);
}

// Round 5
// 1503.098 us; speedup vs baseline: 10.4765x; 1.0022x over previous
//
#include <hip/hip_runtime.h>

// Decoder block, MI355X gfx950. ALL float tensors f32 (per reference); ints
// int32; output f32. GEMMs + attention use bf16 MFMA internally, f32
// accumulate; residual stream kept in f32.

#define BB 16
#define SS 1024
#define DD 512
#define HH 8
#define DH 64
#define KTOT 1792          // 1024 + 512 + 256 pyramid keys
#define NROW (BB*SS)       // 16384

typedef unsigned short u16;
typedef __attribute__((ext_vector_type(8))) u16 u16x8;
typedef __attribute__((ext_vector_type(8))) short s16x8;
typedef __attribute__((ext_vector_type(4))) float f32x4;

__device__ __forceinline__ float b2f(u16 u) {
    return __uint_as_float(((unsigned int)u) << 16);
}
__device__ __forceinline__ u16 f2b(float f) {
    unsigned int u = __float_as_uint(f);
    return (u16)((u + 0x7FFF + ((u >> 16) & 1)) >> 16);
}
__device__ __forceinline__ s16x8 u2s8(u16x8 u) {
    union { u16x8 u; s16x8 s; } x; x.u = u; return x.s;
}
__device__ __forceinline__ f32x4 mfma16(s16x8 a, s16x8 b, f32x4 c) {
    return __builtin_amdgcn_mfma_f32_16x16x32_bf16(a, b, c, 0, 0, 0);
}
__device__ __forceinline__ float wave_sum(float v) {
    #pragma unroll
    for (int m = 1; m < 64; m <<= 1) v += __shfl_xor(v, m, 64);
    return v;
}

// ---------------- embed + LN1 : one wave per (b,s) row, f32 in/out ----------------
__global__ __launch_bounds__(256) void embed_ln_k(
    const int* __restrict__ in_ex, const int* __restrict__ in_cat,
    const int* __restrict__ in_res, const float* __restrict__ in_pos,
    const float* __restrict__ E_res, const float* __restrict__ E_ex,
    const float* __restrict__ E_cat, const float* __restrict__ g,
    const float* __restrict__ be, float* __restrict__ out)
{
    int wave = threadIdx.x >> 6, lane = threadIdx.x & 63;
    int row = blockIdx.x * 4 + wave;          // < 16384
    int res = in_res[row];
    int ex  = in_ex[row] + 10000 * res;
    int cat = in_cat[row] + 300 * res;
    int d0 = lane * 8;
    const float* pr = &E_res[(size_t)res * DD + d0];
    const float* pe = &E_ex[(size_t)ex * DD + d0];
    const float* pc = &E_cat[(size_t)cat * DD + d0];
    const float* pp = &in_pos[(size_t)row * DD + d0];
    float x[8]; float s = 0.f;
    #pragma unroll
    for (int j = 0; j < 8; j++) { x[j] = pr[j] + pe[j] + pc[j] + pp[j]; s += x[j]; }
    s = wave_sum(s);
    float mean = s * (1.0f / DD);
    float vs = 0.f;
    #pragma unroll
    for (int j = 0; j < 8; j++) { float d = x[j] - mean; vs += d * d; }
    vs = wave_sum(vs);
    float rstd = rsqrtf(vs * (1.0f / DD) + 1e-5f);
    #pragma unroll
    for (int j = 0; j < 8; j++)
        out[(size_t)row * DD + d0 + j] = (x[j] - mean) * rstd * g[d0 + j] + be[d0 + j];
}

// ---------------- generic row LayerNorm: f32 in, f32 or bf16 out ----------------
template<bool OUTB>
__global__ __launch_bounds__(256) void ln_k(
    const float* __restrict__ x, const float* __restrict__ g,
    const float* __restrict__ be, void* __restrict__ outv)
{
    int wave = threadIdx.x >> 6, lane = threadIdx.x & 63;
    int row = blockIdx.x * 4 + wave;
    int d0 = lane * 8;
    const float* px = &x[(size_t)row * DD + d0];
    float xv[8]; float s = 0.f;
    #pragma unroll
    for (int j = 0; j < 8; j++) { xv[j] = px[j]; s += xv[j]; }
    s = wave_sum(s);
    float mean = s * (1.0f / DD);
    float vs = 0.f;
    #pragma unroll
    for (int j = 0; j < 8; j++) { float d = xv[j] - mean; vs += d * d; }
    vs = wave_sum(vs);
    float rstd = rsqrtf(vs * (1.0f / DD) + 1e-5f);
    #pragma unroll
    for (int j = 0; j < 8; j++) {
        float v = (xv[j] - mean) * rstd * g[d0 + j] + be[d0 + j];
        if (OUTB) ((u16*)outv)[(size_t)row * DD + d0 + j] = f2b(v);
        else      ((float*)outv)[(size_t)row * DD + d0 + j] = v;
    }
}

// ---------------- weight transpose + cast: f32 W[k][n] -> bf16 Wt[n][k] ----------------
__global__ __launch_bounds__(256) void transpose_k(const float* __restrict__ src, u16* __restrict__ dst)
{
    int idx = blockIdx.x * 256 + threadIdx.x;   // 262144 total
    int n = idx & 511, k = idx >> 9;
    dst[n * 512 + k] = f2b(src[k * 512 + n]);
}

// ---------------- K pyramid levels 1-2 from level 0 already in KP ----------------
// KP layout (B,H,1792,64); keys 0..1023 pre-filled by the K-projection GEMM.
__global__ __launch_bounds__(256) void pool_k12_k(u16* __restrict__ KP)
{
    int idx = blockIdx.x * 256 + threadIdx.x;   // 16*8*768*64 = 6291456
    int d = idx & 63;
    int t = idx >> 6;
    int k12 = t % 768;
    int bh = t / 768;
    int s0, f;
    if (k12 < 512) { s0 = 2 * k12; f = 2; } else { s0 = 4 * (k12 - 512); f = 4; }
    size_t base = (size_t)bh * KTOT * DH;
    float acc = 0.f;
    for (int i = 0; i < f; i++)
        acc += b2f(KP[base + (size_t)(s0 + i) * DH + d]);
    KP[base + (size_t)(1024 + k12) * DH + d] = f2b(acc * (1.0f / (float)f));
}

// ---------------- V pyramid pool, transposed: (B,S,D) -> (B,H,64,1792) ----------------
__global__ __launch_bounds__(256) void pool_vt_k(const u16* __restrict__ Vp, u16* __restrict__ VPt)
{
    int key = blockIdx.x * 256 + threadIdx.x;   // 0..1791
    int d = blockIdx.y;                         // 0..63
    int bh = blockIdx.z;                        // 0..127
    int h = bh & 7, b = bh >> 3;
    int s0, f;
    if (key < 1024)      { s0 = key; f = 1; }
    else if (key < 1536) { s0 = 2 * (key - 1024); f = 2; }
    else                 { s0 = 4 * (key - 1536); f = 4; }
    float acc = 0.f;
    for (int i = 0; i < f; i++)
        acc += b2f(Vp[((size_t)(b * SS + s0 + i)) * DD + h * DH + d]);
    VPt[((size_t)bh * DH + d) * KTOT + key] = f2b(acc * (1.0f / (float)f));
}

// ---------------- MFMA GEMM: C(M,512) = A(M,512) @ W(512,512) + bias [relu] [+resid] ----------------
// KLAY: write bf16 output permuted into KP layout (B,H,1792,64) level-0 region.
template<bool AF32, bool RELU, bool RES, bool OUTB, bool KLAY>
__global__ __launch_bounds__(256) void gemm_k(
    const void* __restrict__ Av, const u16* __restrict__ Wt,
    const float* __restrict__ bias, const float* __restrict__ resid,
    void* __restrict__ Cv, int M, int K)
{
    const int N = 512;
    __shared__ __align__(16) u16 As[128 * 40];
    __shared__ __align__(16) u16 Bs[128 * 40];
    int tid = threadIdx.x;
    int wave = tid >> 6, lane = tid & 63;
    int quad = lane >> 4, l16 = lane & 15;
    int m0 = blockIdx.y * 128, n0 = blockIdx.x * 128;
    int wm = (wave >> 1) * 64, wn = (wave & 1) * 64;
    int r = tid >> 1, cg = (tid & 1) * 16;
    f32x4 acc[4][4];
    #pragma unroll
    for (int i = 0; i < 4; i++)
        #pragma unroll
        for (int j = 0; j < 4; j++)
            #pragma unroll
            for (int rr = 0; rr < 4; rr++) acc[i][j][rr] = 0.f;

    for (int k0 = 0; k0 < K; k0 += 32) {
        __syncthreads();
        if (AF32) {
            const float* src = &((const float*)Av)[(size_t)(m0 + r) * K + k0 + cg];
            u16x8 lo, hi;
            #pragma unroll
            for (int j = 0; j < 8; j++) { lo[j] = f2b(src[j]); hi[j] = f2b(src[j + 8]); }
            *(u16x8*)&As[r * 40 + cg] = lo;
            *(u16x8*)&As[r * 40 + cg + 8] = hi;
        } else {
            const u16* src = &((const u16*)Av)[(size_t)(m0 + r) * K + k0 + cg];
            *(u16x8*)&As[r * 40 + cg] = *(const u16x8*)&src[0];
            *(u16x8*)&As[r * 40 + cg + 8] = *(const u16x8*)&src[8];
        }
        {
            const u16* src = &Wt[(size_t)(n0 + r) * K + k0 + cg];
            *(u16x8*)&Bs[r * 40 + cg] = *(const u16x8*)&src[0];
            *(u16x8*)&Bs[r * 40 + cg + 8] = *(const u16x8*)&src[8];
        }
        __syncthreads();
        s16x8 af[4], bfr[4];
        #pragma unroll
        for (int i = 0; i < 4; i++)
            af[i] = u2s8(*(const u16x8*)&As[(wm + i * 16 + l16) * 40 + quad * 8]);
        #pragma unroll
        for (int j = 0; j < 4; j++)
            bfr[j] = u2s8(*(const u16x8*)&Bs[(wn + j * 16 + l16) * 40 + quad * 8]);
        #pragma unroll
        for (int i = 0; i < 4; i++)
            #pragma unroll
            for (int j = 0; j < 4; j++)
                acc[i][j] = mfma16(af[i], bfr[j], acc[i][j]);
    }

    #pragma unroll
    for (int j = 0; j < 4; j++) {
        int col = n0 + wn + j * 16 + l16;
        float bv = bias[col];
        #pragma unroll
        for (int i = 0; i < 4; i++) {
            int rowb = m0 + wm + i * 16 + quad * 4;
            #pragma unroll
            for (int rr = 0; rr < 4; rr++) {
                float v = acc[i][j][rr] + bv;
                if (RELU) v = fmaxf(v, 0.f);
                int row = rowb + rr;
                if (RES) v += resid[(size_t)row * N + col];
                if (KLAY) {
                    int b_ = row >> 10, s_ = row & 1023;
                    size_t dst = (((size_t)(b_ * HH + (col >> 6)) * KTOT) + s_) * DH + (col & 63);
                    ((u16*)Cv)[dst] = f2b(v);
                } else if (OUTB) {
                    ((u16*)Cv)[(size_t)row * N + col] = f2b(v);
                } else {
                    ((float*)Cv)[(size_t)row * N + col] = v;
                }
            }
        }
    }
}

// ---------------- MFMA flash pyramid attention, A-layout softmax ----------------
// grid (16 qtiles, H, B) x 256thr = 4 waves; each wave owns 16 queries.
// K from KP (B,H,1792,64); V from transposed pooled VPt (B,H,64,1792).
// Per 64-key chunk: QK^T (C-layout) -> masked f32 scores through per-wave LDS
// -> A-layout, softmax reductions in-register + 2 cross-quad shuffles -> PV.
__global__ __launch_bounds__(256) void attn_k(
    const u16* __restrict__ Qp, const u16* __restrict__ KP,
    const u16* __restrict__ VPt, u16* __restrict__ Hout)
{
    __shared__ float Sc[4][16 * 68];   // per-wave 16 q-rows x 64 keys, stride 68
    int tid = threadIdx.x;
    int wave = tid >> 6, lane = tid & 63;
    int quad = lane >> 4, l16 = lane & 15;
    int qt = blockIdx.x, h = blockIdx.y, b = blockIdx.z;
    int q0 = qt * 64 + wave * 16;
    int qmax = q0 + 15;

    const u16* qrow = Qp + ((size_t)(b * SS + q0 + l16)) * DD + h * DH;
    s16x8 qa0 = u2s8(*(const u16x8*)&qrow[quad * 8]);
    s16x8 qa1 = u2s8(*(const u16x8*)&qrow[32 + quad * 8]);
    const u16* Kb = KP  + ((size_t)(b * HH + h)) * KTOT * DH;
    const u16* Vt = VPt + ((size_t)(b * HH + h)) * DH * KTOT;

    f32x4 o[4];
    #pragma unroll
    for (int j = 0; j < 4; j++)
        #pragma unroll
        for (int r = 0; r < 4; r++) o[j][r] = 0.f;
    float m = -INFINITY;   // running max for q-row l16 (replicated across quads)
    float l = 0.f;
    float* Sw = &Sc[wave][0];

    const int lev_cc0[3] = {0, 16, 24};   // in 64-key chunks
    const int lev_cnt[3] = {16, 8, 4};

    for (int lv = 0; lv < 3; lv++) {
        for (int cc = 0; cc < lev_cnt[lv]; cc++) {
            int kbase = (lev_cc0[lv] + cc) * 64;
            int efirst = (lv == 0) ? kbase
                       : (lv == 1) ? 2 * (kbase - 1024) + 1
                                   : 4 * (kbase - 1536) + 3;
            if (efirst > qmax) break;

            // QK^T: four 16-key groups; write masked f32 scores to LDS
            #pragma unroll
            for (int t = 0; t < 4; t++) {
                int kb0 = kbase + t * 16;
                const u16* kr = &Kb[(size_t)(kb0 + l16) * DH];
                s16x8 kf0 = u2s8(*(const u16x8*)&kr[quad * 8]);
                s16x8 kf1 = u2s8(*(const u16x8*)&kr[32 + quad * 8]);
                f32x4 z;
                #pragma unroll
                for (int r = 0; r < 4; r++) z[r] = 0.f;
                z = mfma16(qa0, kf0, z);
                z = mfma16(qa1, kf1, z);
                int key = kb0 + l16;
                int e = (lv == 0) ? key
                      : (lv == 1) ? 2 * (key - 1024) + 1
                                  : 4 * (key - 1536) + 3;
                #pragma unroll
                for (int r = 0; r < 4; r++) {
                    int q = q0 + quad * 4 + r;
                    Sw[(quad * 4 + r) * 68 + t * 16 + l16] =
                        (q >= e) ? z[r] * 0.125f : -1e30f;
                }
            }
            asm volatile("s_waitcnt lgkmcnt(0)" ::: "memory");

            // A-layout read: row l16, keys quad*8+j (frag0) / 32+quad*8+j (frag1)
            float sv[16];
            {
                const float* base0 = &Sw[l16 * 68 + quad * 8];
                f32x4 a0 = *(const f32x4*)&base0[0];
                f32x4 a1 = *(const f32x4*)&base0[4];
                f32x4 a2 = *(const f32x4*)&base0[32];
                f32x4 a3 = *(const f32x4*)&base0[36];
                #pragma unroll
                for (int j = 0; j < 4; j++) {
                    sv[j] = a0[j]; sv[4 + j] = a1[j];
                    sv[8 + j] = a2[j]; sv[12 + j] = a3[j];
                }
            }

            // softmax over 64 keys of row l16: in-register + 2 shuffles
            float cmax = sv[0];
            #pragma unroll
            for (int j = 1; j < 16; j++) cmax = fmaxf(cmax, sv[j]);
            cmax = fmaxf(cmax, __shfl_xor(cmax, 16, 64));
            cmax = fmaxf(cmax, __shfl_xor(cmax, 32, 64));
            float newm = fmaxf(m, cmax);
            float al = __expf(m - newm);
            float p[16]; float ps = 0.f;
            #pragma unroll
            for (int j = 0; j < 16; j++) { p[j] = __expf(sv[j] - newm); ps += p[j]; }
            ps += __shfl_xor(ps, 16, 64);
            ps += __shfl_xor(ps, 32, 64);
            l = l * al + ps;
            m = newm;

            // rescale o (C-layout rows quad*4+r): fetch alpha of those rows
            float alr[4];
            #pragma unroll
            for (int r = 0; r < 4; r++) alr[r] = __shfl(al, quad * 4 + r, 64);
            #pragma unroll
            for (int j = 0; j < 4; j++)
                #pragma unroll
                for (int r = 0; r < 4; r++) o[j][r] *= alr[r];

            // pack P to bf16 A-frags
            u16x8 pk0, pk1;
            #pragma unroll
            for (int j = 0; j < 8; j++) { pk0[j] = f2b(p[j]); pk1[j] = f2b(p[8 + j]); }
            s16x8 pf0 = u2s8(pk0), pf1 = u2s8(pk1);

            // PV: 4 dh-tiles of 16 columns
            #pragma unroll
            for (int j = 0; j < 4; j++) {
                const u16* vr = &Vt[(size_t)(j * 16 + l16) * KTOT + kbase];
                o[j] = mfma16(pf0, u2s8(*(const u16x8*)&vr[quad * 8]), o[j]);
                o[j] = mfma16(pf1, u2s8(*(const u16x8*)&vr[32 + quad * 8]), o[j]);
            }
        }
    }

    // epilogue
    float il = 1.0f / l;               // row l16
    float ilr[4];
    #pragma unroll
    for (int r = 0; r < 4; r++) ilr[r] = __shfl(il, quad * 4 + r, 64);
    #pragma unroll
    for (int r = 0; r < 4; r++) {
        int q = q0 + quad * 4 + r;
        #pragma unroll
        for (int j = 0; j < 4; j++)
            Hout[((size_t)(b * SS + q)) * DD + h * DH + j * 16 + l16] = f2b(o[j][r] * ilr[r]);
    }
}

extern "C" void kernel_launch(void* const* d_in, const int* in_sizes, int n_in,
                              void* d_out, int out_size, void* d_ws, size_t ws_size,
                              hipStream_t stream)
{
    (void)in_sizes; (void)n_in; (void)out_size; (void)ws_size;
    const int* in_ex  = (const int*)d_in[0];
    const int* in_cat = (const int*)d_in[1];
    const int* in_res = (const int*)d_in[2];
    const float* in_pos = (const float*)d_in[3];
    const float* en_out = (const float*)d_in[4];
    const float* E_res  = (const float*)d_in[5];
    const float* E_ex   = (const float*)d_in[6];
    const float* E_cat  = (const float*)d_in[7];
    const float* g1 = (const float*)d_in[8],  *be1 = (const float*)d_in[9];
    const float* g2 = (const float*)d_in[10], *be2 = (const float*)d_in[11];
    const float* g3 = (const float*)d_in[12], *be3 = (const float*)d_in[13];
    const float* Wq1 = (const float*)d_in[14], *bq1 = (const float*)d_in[15];
    const float* Wk1 = (const float*)d_in[16], *bk1 = (const float*)d_in[17];
    const float* Wv1 = (const float*)d_in[18], *bv1 = (const float*)d_in[19];
    const float* Wo1 = (const float*)d_in[20], *bo1 = (const float*)d_in[21];
    const float* Wq2 = (const float*)d_in[22], *bq2 = (const float*)d_in[23];
    const float* Wk2 = (const float*)d_in[24], *bk2 = (const float*)d_in[25];
    const float* Wv2 = (const float*)d_in[26], *bv2 = (const float*)d_in[27];
    const float* Wo2 = (const float*)d_in[28], *bo2 = (const float*)d_in[29];
    const float* fW1 = (const float*)d_in[30], *fb1 = (const float*)d_in[31];
    const float* fW2 = (const float*)d_in[32], *fb2 = (const float*)d_in[33];

    char* ws = (char*)d_ws;
    const size_t U = (size_t)NROW * DD * 2;        // 16.78 MB
    float* x1 = (float*)(ws);                      // 2U f32  [ph4: en bf16 in 1st U; then x3 f32]
    u16* qb   = (u16*)(ws + 2 * U);                // 1U
    u16* vb   = (u16*)(ws + 3 * U);                // 1U
    u16* hb   = (u16*)(ws + 4 * U);                // 1U  [ph5: ff1]
    u16* kp   = (u16*)(ws + 5 * U);                // 1.75U (B,H,1792,64)
    u16* vpt  = (u16*)(ws + 5 * U + 7 * U / 4);    // 1.75U (B,H,64,1792)
    u16* wt   = (u16*)(ws + 8 * U + U / 2);        // 10 x 512KB bf16 transposed weights
    // peak ws use: 8.5U + 5.24MB ~= 148 MB (same as round 4's proven footprint)
    float* x2 = (float*)d_out;                     // d_out doubles as x2 (fully overwritten at end)
    u16* en = (u16*)(ws);                          // phase-4 alias of dead x1 slot
    float* x3 = x1;                                // phase-4 output slot
    float* x4 = (float*)(ws + 5 * U);              // phase-5 alias over kp/vpt (dead)
    u16* ff1 = hb;                                 // phase-5 alias

    const float* wsrc[10] = {Wq1, Wk1, Wv1, Wo1, Wq2, Wk2, Wv2, Wo2, fW1, fW2};
    for (int i = 0; i < 10; i++)
        transpose_k<<<1024, 256, 0, stream>>>(wsrc[i], wt + (size_t)i * 262144);
    u16* tWq1 = wt,            *tWk1 = wt + 262144,   *tWv1 = wt + 2*262144, *tWo1 = wt + 3*262144;
    u16* tWq2 = wt + 4*262144, *tWk2 = wt + 5*262144, *tWv2 = wt + 6*262144, *tWo2 = wt + 7*262144;
    u16* tF1  = wt + 8*262144, *tF2  = wt + 9*262144;

    dim3 ggrid(4, 128);
    dim3 agrid(16, HH, BB);
    dim3 vtgrid(7, 64, 128);

    // phase 2: x1 = LN1(embed sum)   (f32)
    embed_ln_k<<<4096, 256, 0, stream>>>(in_ex, in_cat, in_res, in_pos,
                                         E_res, E_ex, E_cat, g1, be1, x1);

    // phase 3: self-attention; x2 = x1 + attn(x1) @ Wo1
    gemm_k<true,false,false,true,false><<<ggrid, 256, 0, stream>>>(x1, tWq1, bq1, nullptr, qb, NROW, 512);
    gemm_k<true,false,false,true,true ><<<ggrid, 256, 0, stream>>>(x1, tWk1, bk1, nullptr, kp, NROW, 512);
    gemm_k<true,false,false,true,false><<<ggrid, 256, 0, stream>>>(x1, tWv1, bv1, nullptr, vb, NROW, 512);
    pool_k12_k<<<24576, 256, 0, stream>>>(kp);
    pool_vt_k<<<vtgrid, 256, 0, stream>>>(vb, vpt);
    attn_k<<<agrid, 256, 0, stream>>>(qb, kp, vpt, hb);
    gemm_k<false,false,true,false,false><<<ggrid, 256, 0, stream>>>(hb, tWo1, bo1, x1, x2, NROW, 512);

    // phase 4: cross-attention; x3 = x2 + attn(q=x2, kv=en) @ Wo2
    ln_k<true><<<4096, 256, 0, stream>>>(en_out, g2, be2, en);
    gemm_k<true,false,false,true,false><<<ggrid, 256, 0, stream>>>(x2, tWq2, bq2, nullptr, qb, NROW, 512);
    gemm_k<false,false,false,true,true ><<<ggrid, 256, 0, stream>>>(en, tWk2, bk2, nullptr, kp, NROW, 512);
    gemm_k<false,false,false,true,false><<<ggrid, 256, 0, stream>>>(en, tWv2, bv2, nullptr, vb, NROW, 512);
    pool_k12_k<<<24576, 256, 0, stream>>>(kp);
    pool_vt_k<<<vtgrid, 256, 0, stream>>>(vb, vpt);
    attn_k<<<agrid, 256, 0, stream>>>(qb, kp, vpt, hb);
    gemm_k<false,false,true,false,false><<<ggrid, 256, 0, stream>>>(hb, tWo2, bo2, x2, x3, NROW, 512);

    // phase 5: x4 = LN3(x3); out = x4 + relu(x4@fW1+fb1)@fW2+fb2
    ln_k<false><<<4096, 256, 0, stream>>>(x3, g3, be3, x4);
    gemm_k<true,true,false,true,false><<<ggrid, 256, 0, stream>>>(x4, tF1, fb1, nullptr, ff1, NROW, 512);
    gemm_k<false,false,true,false,false><<<ggrid, 256, 0, stream>>>(ff1, tF2, fb2, x4, (float*)d_out, NROW, 512);
}

// Round 6
// 899.529 us; speedup vs baseline: 17.5061x; 1.6710x over previous
//
#include <hip/hip_runtime.h>

// Decoder block, MI355X gfx950. ALL float tensors f32 (per reference); ints
// int32; output f32. GEMMs + attention use bf16 MFMA internally, f32
// accumulate; residual stream kept in f32.

#define BB 16
#define SS 1024
#define DD 512
#define HH 8
#define DH 64
#define KTOT 1792          // 1024 + 512 + 256 pyramid keys
#define NROW (BB*SS)       // 16384

typedef unsigned short u16;
typedef __attribute__((ext_vector_type(8))) u16 u16x8;
typedef __attribute__((ext_vector_type(8))) short s16x8;
typedef __attribute__((ext_vector_type(4))) float f32x4;

__device__ __forceinline__ float b2f(u16 u) {
    return __uint_as_float(((unsigned int)u) << 16);
}
__device__ __forceinline__ u16 f2b(float f) {
    unsigned int u = __float_as_uint(f);
    return (u16)((u + 0x7FFF + ((u >> 16) & 1)) >> 16);
}
__device__ __forceinline__ s16x8 u2s8(u16x8 u) {
    union { u16x8 u; s16x8 s; } x; x.u = u; return x.s;
}
__device__ __forceinline__ f32x4 mfma16(s16x8 a, s16x8 b, f32x4 c) {
    return __builtin_amdgcn_mfma_f32_16x16x32_bf16(a, b, c, 0, 0, 0);
}
__device__ __forceinline__ float wave_sum(float v) {
    #pragma unroll
    for (int m = 1; m < 64; m <<= 1) v += __shfl_xor(v, m, 64);
    return v;
}

// ---------------- embed + LN1 : one wave per (b,s) row, f32 in/out ----------------
__global__ __launch_bounds__(256) void embed_ln_k(
    const int* __restrict__ in_ex, const int* __restrict__ in_cat,
    const int* __restrict__ in_res, const float* __restrict__ in_pos,
    const float* __restrict__ E_res, const float* __restrict__ E_ex,
    const float* __restrict__ E_cat, const float* __restrict__ g,
    const float* __restrict__ be, float* __restrict__ out)
{
    int wave = threadIdx.x >> 6, lane = threadIdx.x & 63;
    int row = blockIdx.x * 4 + wave;          // < 16384
    int res = in_res[row];
    int ex  = in_ex[row] + 10000 * res;
    int cat = in_cat[row] + 300 * res;
    int d0 = lane * 8;
    const float* pr = &E_res[(size_t)res * DD + d0];
    const float* pe = &E_ex[(size_t)ex * DD + d0];
    const float* pc = &E_cat[(size_t)cat * DD + d0];
    const float* pp = &in_pos[(size_t)row * DD + d0];
    float x[8]; float s = 0.f;
    #pragma unroll
    for (int j = 0; j < 8; j++) { x[j] = pr[j] + pe[j] + pc[j] + pp[j]; s += x[j]; }
    s = wave_sum(s);
    float mean = s * (1.0f / DD);
    float vs = 0.f;
    #pragma unroll
    for (int j = 0; j < 8; j++) { float d = x[j] - mean; vs += d * d; }
    vs = wave_sum(vs);
    float rstd = rsqrtf(vs * (1.0f / DD) + 1e-5f);
    #pragma unroll
    for (int j = 0; j < 8; j++)
        out[(size_t)row * DD + d0 + j] = (x[j] - mean) * rstd * g[d0 + j] + be[d0 + j];
}

// ---------------- generic row LayerNorm: f32 in, f32 or bf16 out ----------------
template<bool OUTB>
__global__ __launch_bounds__(256) void ln_k(
    const float* __restrict__ x, const float* __restrict__ g,
    const float* __restrict__ be, void* __restrict__ outv)
{
    int wave = threadIdx.x >> 6, lane = threadIdx.x & 63;
    int row = blockIdx.x * 4 + wave;
    int d0 = lane * 8;
    const float* px = &x[(size_t)row * DD + d0];
    float xv[8]; float s = 0.f;
    #pragma unroll
    for (int j = 0; j < 8; j++) { xv[j] = px[j]; s += xv[j]; }
    s = wave_sum(s);
    float mean = s * (1.0f / DD);
    float vs = 0.f;
    #pragma unroll
    for (int j = 0; j < 8; j++) { float d = xv[j] - mean; vs += d * d; }
    vs = wave_sum(vs);
    float rstd = rsqrtf(vs * (1.0f / DD) + 1e-5f);
    #pragma unroll
    for (int j = 0; j < 8; j++) {
        float v = (xv[j] - mean) * rstd * g[d0 + j] + be[d0 + j];
        if (OUTB) ((u16*)outv)[(size_t)row * DD + d0 + j] = f2b(v);
        else      ((float*)outv)[(size_t)row * DD + d0 + j] = v;
    }
}

// ---------------- weight transpose + cast: f32 W[k][n] -> bf16 Wt[n][k] ----------------
__global__ __launch_bounds__(256) void transpose_k(const float* __restrict__ src, u16* __restrict__ dst)
{
    int idx = blockIdx.x * 256 + threadIdx.x;   // 262144 total
    int n = idx & 511, k = idx >> 9;
    dst[n * 512 + k] = f2b(src[k * 512 + n]);
}

// ---------------- K pyramid levels 1-2 from level 0 already in KP ----------------
// KP layout (B,H,1792,64); keys 0..1023 pre-filled by the K-projection GEMM.
__global__ __launch_bounds__(256) void pool_k12_k(u16* __restrict__ KP)
{
    int idx = blockIdx.x * 256 + threadIdx.x;   // 16*8*768*64 = 6291456
    int d = idx & 63;
    int t = idx >> 6;
    int k12 = t % 768;
    int bh = t / 768;
    int s0, f;
    if (k12 < 512) { s0 = 2 * k12; f = 2; } else { s0 = 4 * (k12 - 512); f = 4; }
    size_t base = (size_t)bh * KTOT * DH;
    float acc = 0.f;
    for (int i = 0; i < f; i++)
        acc += b2f(KP[base + (size_t)(s0 + i) * DH + d]);
    KP[base + (size_t)(1024 + k12) * DH + d] = f2b(acc * (1.0f / (float)f));
}

// ---------------- V pyramid pool, transposed: (B,S,D) -> (B,H,64,1792) ----------------
__global__ __launch_bounds__(256) void pool_vt_k(const u16* __restrict__ Vp, u16* __restrict__ VPt)
{
    int key = blockIdx.x * 256 + threadIdx.x;   // 0..1791
    int d = blockIdx.y;                         // 0..63
    int bh = blockIdx.z;                        // 0..127
    int h = bh & 7, b = bh >> 3;
    int s0, f;
    if (key < 1024)      { s0 = key; f = 1; }
    else if (key < 1536) { s0 = 2 * (key - 1024); f = 2; }
    else                 { s0 = 4 * (key - 1536); f = 4; }
    float acc = 0.f;
    for (int i = 0; i < f; i++)
        acc += b2f(Vp[((size_t)(b * SS + s0 + i)) * DD + h * DH + d]);
    VPt[((size_t)bh * DH + d) * KTOT + key] = f2b(acc * (1.0f / (float)f));
}

// ---------------- MFMA GEMM: C(M,512) = A(M,512) @ W(512,512) + bias [relu] [+resid] ----------------
// KLAY: write bf16 output permuted into KP layout (B,H,1792,64) level-0 region.
template<bool AF32, bool RELU, bool RES, bool OUTB, bool KLAY>
__global__ __launch_bounds__(256) void gemm_k(
    const void* __restrict__ Av, const u16* __restrict__ Wt,
    const float* __restrict__ bias, const float* __restrict__ resid,
    void* __restrict__ Cv, int M, int K)
{
    const int N = 512;
    __shared__ __align__(16) u16 As[128 * 40];
    __shared__ __align__(16) u16 Bs[128 * 40];
    int tid = threadIdx.x;
    int wave = tid >> 6, lane = tid & 63;
    int quad = lane >> 4, l16 = lane & 15;
    int m0 = blockIdx.y * 128, n0 = blockIdx.x * 128;
    int wm = (wave >> 1) * 64, wn = (wave & 1) * 64;
    int r = tid >> 1, cg = (tid & 1) * 16;
    f32x4 acc[4][4];
    #pragma unroll
    for (int i = 0; i < 4; i++)
        #pragma unroll
        for (int j = 0; j < 4; j++)
            #pragma unroll
            for (int rr = 0; rr < 4; rr++) acc[i][j][rr] = 0.f;

    for (int k0 = 0; k0 < K; k0 += 32) {
        __syncthreads();
        if (AF32) {
            const float* src = &((const float*)Av)[(size_t)(m0 + r) * K + k0 + cg];
            u16x8 lo, hi;
            #pragma unroll
            for (int j = 0; j < 8; j++) { lo[j] = f2b(src[j]); hi[j] = f2b(src[j + 8]); }
            *(u16x8*)&As[r * 40 + cg] = lo;
            *(u16x8*)&As[r * 40 + cg + 8] = hi;
        } else {
            const u16* src = &((const u16*)Av)[(size_t)(m0 + r) * K + k0 + cg];
            *(u16x8*)&As[r * 40 + cg] = *(const u16x8*)&src[0];
            *(u16x8*)&As[r * 40 + cg + 8] = *(const u16x8*)&src[8];
        }
        {
            const u16* src = &Wt[(size_t)(n0 + r) * K + k0 + cg];
            *(u16x8*)&Bs[r * 40 + cg] = *(const u16x8*)&src[0];
            *(u16x8*)&Bs[r * 40 + cg + 8] = *(const u16x8*)&src[8];
        }
        __syncthreads();
        s16x8 af[4], bfr[4];
        #pragma unroll
        for (int i = 0; i < 4; i++)
            af[i] = u2s8(*(const u16x8*)&As[(wm + i * 16 + l16) * 40 + quad * 8]);
        #pragma unroll
        for (int j = 0; j < 4; j++)
            bfr[j] = u2s8(*(const u16x8*)&Bs[(wn + j * 16 + l16) * 40 + quad * 8]);
        #pragma unroll
        for (int i = 0; i < 4; i++)
            #pragma unroll
            for (int j = 0; j < 4; j++)
                acc[i][j] = mfma16(af[i], bfr[j], acc[i][j]);
    }

    #pragma unroll
    for (int j = 0; j < 4; j++) {
        int col = n0 + wn + j * 16 + l16;
        float bv = bias[col];
        #pragma unroll
        for (int i = 0; i < 4; i++) {
            int rowb = m0 + wm + i * 16 + quad * 4;
            #pragma unroll
            for (int rr = 0; rr < 4; rr++) {
                float v = acc[i][j][rr] + bv;
                if (RELU) v = fmaxf(v, 0.f);
                int row = rowb + rr;
                if (RES) v += resid[(size_t)row * N + col];
                if (KLAY) {
                    int b_ = row >> 10, s_ = row & 1023;
                    size_t dst = (((size_t)(b_ * HH + (col >> 6)) * KTOT) + s_) * DH + (col & 63);
                    ((u16*)Cv)[dst] = f2b(v);
                } else if (OUTB) {
                    ((u16*)Cv)[(size_t)row * N + col] = f2b(v);
                } else {
                    ((float*)Cv)[(size_t)row * N + col] = v;
                }
            }
        }
    }
}

// ---------------- MFMA flash pyramid attention, block-shared LDS K/V ----------------
// 512 blocks x 512 threads (8 waves). Block owns (b,h) with a 4-way query
// split (x): wave w handles q-tiles t0 = x+4w and 63-t0 (balanced pairing).
// Per 64-key chunk: K-chunk (64x64) and V-chunk (64 dh x 64 keys, from VPt)
// staged into LDS once per block (register-prefetched one chunk ahead);
// all waves compute QK/softmax/PV from LDS. Uniform 28-chunk loop.
__global__ __launch_bounds__(512) void attn_k(
    const u16* __restrict__ Qp, const u16* __restrict__ KP,
    const u16* __restrict__ VPt, u16* __restrict__ Hout)
{
    __shared__ __align__(16) u16 Ksh[64 * 72];   // keys x dh, stride 72
    __shared__ __align__(16) u16 Vsh[64 * 72];   // dh x keys, stride 72
    __shared__ float Sc[8][16 * 68];             // per-wave scores
    int tid = threadIdx.x;
    int wave = tid >> 6, lane = tid & 63;
    int quad = lane >> 4, l16 = lane & 15;
    // XCD-swizzled decode: id = (bh&7) + 8*(x + 4*(bh>>3))
    int id = blockIdx.x;
    int h = id & 7;
    int inner = id >> 3;
    int x = inner & 3, b = inner >> 2;

    int t0 = x + 4 * wave;                 // 0..31
    int tiles[2] = { t0, 63 - t0 };

    const u16* Kb = KP  + ((size_t)(b * HH + h)) * KTOT * DH;
    const u16* Vt = VPt + ((size_t)(b * HH + h)) * DH * KTOT;

    s16x8 qa[2][2];
    f32x4 o[2][4];
    float mrun[2] = {-INFINITY, -INFINITY}, lrun[2] = {0.f, 0.f};
    #pragma unroll
    for (int c = 0; c < 2; c++) {
        int q0 = tiles[c] * 16;
        const u16* qrow = Qp + ((size_t)(b * SS + q0 + l16)) * DD + h * DH;
        qa[c][0] = u2s8(*(const u16x8*)&qrow[quad * 8]);
        qa[c][1] = u2s8(*(const u16x8*)&qrow[32 + quad * 8]);
        #pragma unroll
        for (int j = 0; j < 4; j++)
            #pragma unroll
            for (int r = 0; r < 4; r++) o[c][j][r] = 0.f;
    }
    float* Sw = &Sc[wave][0];

    int srow = tid >> 3, sunit = tid & 7;  // staging: 64 rows x 8 units of 16B
    // prefetch chunk 0
    u16x8 kreg = *(const u16x8*)&Kb[(size_t)tid * 8];
    u16x8 vreg = *(const u16x8*)&Vt[(size_t)srow * KTOT + sunit * 8];

    for (int ch = 0; ch < 28; ch++) {
        int kbase = ch * 64;
        int lv = (ch < 16) ? 0 : (ch < 24) ? 1 : 2;
        __syncthreads();   // prior chunk's LDS reads done
        *(u16x8*)&Ksh[srow * 72 + sunit * 8] = kreg;
        *(u16x8*)&Vsh[srow * 72 + sunit * 8] = vreg;
        __syncthreads();   // staging visible
        if (ch + 1 < 28) { // prefetch next chunk (overlaps compute below)
            int nb = (ch + 1) * 64;
            kreg = *(const u16x8*)&Kb[(size_t)nb * DH + tid * 8];
            vreg = *(const u16x8*)&Vt[(size_t)srow * KTOT + nb + sunit * 8];
        }

        #pragma unroll
        for (int c = 0; c < 2; c++) {
            int q0 = tiles[c] * 16;
            int qmax = q0 + 15;
            int efirst = (lv == 0) ? kbase
                       : (lv == 1) ? 2 * (kbase - 1024) + 1
                                   : 4 * (kbase - 1536) + 3;
            if (efirst > qmax) continue;   // wave-uniform

            // QK^T from LDS K
            #pragma unroll
            for (int t = 0; t < 4; t++) {
                const u16* kr = &Ksh[(t * 16 + l16) * 72];
                s16x8 kf0 = u2s8(*(const u16x8*)&kr[quad * 8]);
                s16x8 kf1 = u2s8(*(const u16x8*)&kr[32 + quad * 8]);
                f32x4 z;
                #pragma unroll
                for (int r = 0; r < 4; r++) z[r] = 0.f;
                z = mfma16(qa[c][0], kf0, z);
                z = mfma16(qa[c][1], kf1, z);
                int key = kbase + t * 16 + l16;
                int e = (lv == 0) ? key
                      : (lv == 1) ? 2 * (key - 1024) + 1
                                  : 4 * (key - 1536) + 3;
                #pragma unroll
                for (int r = 0; r < 4; r++) {
                    int q = q0 + quad * 4 + r;
                    Sw[(quad * 4 + r) * 68 + t * 16 + l16] =
                        (q >= e) ? z[r] * 0.125f : -1e30f;
                }
            }
            asm volatile("s_waitcnt lgkmcnt(0)" ::: "memory");

            // A-layout read: row l16, 16 keys per lane
            float sv[16];
            {
                const float* base0 = &Sw[l16 * 68 + quad * 8];
                f32x4 a0 = *(const f32x4*)&base0[0];
                f32x4 a1 = *(const f32x4*)&base0[4];
                f32x4 a2 = *(const f32x4*)&base0[32];
                f32x4 a3 = *(const f32x4*)&base0[36];
                #pragma unroll
                for (int j = 0; j < 4; j++) {
                    sv[j] = a0[j]; sv[4 + j] = a1[j];
                    sv[8 + j] = a2[j]; sv[12 + j] = a3[j];
                }
            }

            float cmax = sv[0];
            #pragma unroll
            for (int j = 1; j < 16; j++) cmax = fmaxf(cmax, sv[j]);
            cmax = fmaxf(cmax, __shfl_xor(cmax, 16, 64));
            cmax = fmaxf(cmax, __shfl_xor(cmax, 32, 64));
            float newm = fmaxf(mrun[c], cmax);
            float al = __expf(mrun[c] - newm);
            float p[16]; float ps = 0.f;
            #pragma unroll
            for (int j = 0; j < 16; j++) { p[j] = __expf(sv[j] - newm); ps += p[j]; }
            ps += __shfl_xor(ps, 16, 64);
            ps += __shfl_xor(ps, 32, 64);
            lrun[c] = lrun[c] * al + ps;
            mrun[c] = newm;

            float alr[4];
            #pragma unroll
            for (int r = 0; r < 4; r++) alr[r] = __shfl(al, quad * 4 + r, 64);
            #pragma unroll
            for (int j = 0; j < 4; j++)
                #pragma unroll
                for (int r = 0; r < 4; r++) o[c][j][r] *= alr[r];

            u16x8 pk0, pk1;
            #pragma unroll
            for (int j = 0; j < 8; j++) { pk0[j] = f2b(p[j]); pk1[j] = f2b(p[8 + j]); }
            s16x8 pf0 = u2s8(pk0), pf1 = u2s8(pk1);

            // PV from LDS V (dh-major rows)
            #pragma unroll
            for (int j = 0; j < 4; j++) {
                const u16* vr = &Vsh[(j * 16 + l16) * 72];
                o[c][j] = mfma16(pf0, u2s8(*(const u16x8*)&vr[quad * 8]), o[c][j]);
                o[c][j] = mfma16(pf1, u2s8(*(const u16x8*)&vr[32 + quad * 8]), o[c][j]);
            }
        }
    }

    // epilogue per tile
    #pragma unroll
    for (int c = 0; c < 2; c++) {
        int q0 = tiles[c] * 16;
        float il = 1.0f / lrun[c];
        float ilr[4];
        #pragma unroll
        for (int r = 0; r < 4; r++) ilr[r] = __shfl(il, quad * 4 + r, 64);
        #pragma unroll
        for (int r = 0; r < 4; r++) {
            int q = q0 + quad * 4 + r;
            #pragma unroll
            for (int j = 0; j < 4; j++)
                Hout[((size_t)(b * SS + q)) * DD + h * DH + j * 16 + l16] = f2b(o[c][j][r] * ilr[r]);
        }
    }
}

extern "C" void kernel_launch(void* const* d_in, const int* in_sizes, int n_in,
                              void* d_out, int out_size, void* d_ws, size_t ws_size,
                              hipStream_t stream)
{
    (void)in_sizes; (void)n_in; (void)out_size; (void)ws_size;
    const int* in_ex  = (const int*)d_in[0];
    const int* in_cat = (const int*)d_in[1];
    const int* in_res = (const int*)d_in[2];
    const float* in_pos = (const float*)d_in[3];
    const float* en_out = (const float*)d_in[4];
    const float* E_res  = (const float*)d_in[5];
    const float* E_ex   = (const float*)d_in[6];
    const float* E_cat  = (const float*)d_in[7];
    const float* g1 = (const float*)d_in[8],  *be1 = (const float*)d_in[9];
    const float* g2 = (const float*)d_in[10], *be2 = (const float*)d_in[11];
    const float* g3 = (const float*)d_in[12], *be3 = (const float*)d_in[13];
    const float* Wq1 = (const float*)d_in[14], *bq1 = (const float*)d_in[15];
    const float* Wk1 = (const float*)d_in[16], *bk1 = (const float*)d_in[17];
    const float* Wv1 = (const float*)d_in[18], *bv1 = (const float*)d_in[19];
    const float* Wo1 = (const float*)d_in[20], *bo1 = (const float*)d_in[21];
    const float* Wq2 = (const float*)d_in[22], *bq2 = (const float*)d_in[23];
    const float* Wk2 = (const float*)d_in[24], *bk2 = (const float*)d_in[25];
    const float* Wv2 = (const float*)d_in[26], *bv2 = (const float*)d_in[27];
    const float* Wo2 = (const float*)d_in[28], *bo2 = (const float*)d_in[29];
    const float* fW1 = (const float*)d_in[30], *fb1 = (const float*)d_in[31];
    const float* fW2 = (const float*)d_in[32], *fb2 = (const float*)d_in[33];

    char* ws = (char*)d_ws;
    const size_t U = (size_t)NROW * DD * 2;        // 16.78 MB
    float* x1 = (float*)(ws);                      // 2U f32  [ph4: en bf16 in 1st U; then x3 f32]
    u16* qb   = (u16*)(ws + 2 * U);                // 1U
    u16* vb   = (u16*)(ws + 3 * U);                // 1U
    u16* hb   = (u16*)(ws + 4 * U);                // 1U  [ph5: ff1]
    u16* kp   = (u16*)(ws + 5 * U);                // 1.75U (B,H,1792,64)
    u16* vpt  = (u16*)(ws + 5 * U + 7 * U / 4);    // 1.75U (B,H,64,1792)
    u16* wt   = (u16*)(ws + 8 * U + U / 2);        // 10 x 512KB bf16 transposed weights
    float* x2 = (float*)d_out;                     // d_out doubles as x2 (fully overwritten at end)
    u16* en = (u16*)(ws);                          // phase-4 alias of dead x1 slot
    float* x3 = x1;                                // phase-4 output slot
    float* x4 = (float*)(ws + 5 * U);              // phase-5 alias over kp/vpt (dead)
    u16* ff1 = hb;                                 // phase-5 alias

    const float* wsrc[10] = {Wq1, Wk1, Wv1, Wo1, Wq2, Wk2, Wv2, Wo2, fW1, fW2};
    for (int i = 0; i < 10; i++)
        transpose_k<<<1024, 256, 0, stream>>>(wsrc[i], wt + (size_t)i * 262144);
    u16* tWq1 = wt,            *tWk1 = wt + 262144,   *tWv1 = wt + 2*262144, *tWo1 = wt + 3*262144;
    u16* tWq2 = wt + 4*262144, *tWk2 = wt + 5*262144, *tWv2 = wt + 6*262144, *tWo2 = wt + 7*262144;
    u16* tF1  = wt + 8*262144, *tF2  = wt + 9*262144;

    dim3 ggrid(4, 128);
    dim3 vtgrid(7, 64, 128);

    // phase 2: x1 = LN1(embed sum)   (f32)
    embed_ln_k<<<4096, 256, 0, stream>>>(in_ex, in_cat, in_res, in_pos,
                                         E_res, E_ex, E_cat, g1, be1, x1);

    // phase 3: self-attention; x2 = x1 + attn(x1) @ Wo1
    gemm_k<true,false,false,true,false><<<ggrid, 256, 0, stream>>>(x1, tWq1, bq1, nullptr, qb, NROW, 512);
    gemm_k<true,false,false,true,true ><<<ggrid, 256, 0, stream>>>(x1, tWk1, bk1, nullptr, kp, NROW, 512);
    gemm_k<true,false,false,true,false><<<ggrid, 256, 0, stream>>>(x1, tWv1, bv1, nullptr, vb, NROW, 512);
    pool_k12_k<<<24576, 256, 0, stream>>>(kp);
    pool_vt_k<<<vtgrid, 256, 0, stream>>>(vb, vpt);
    attn_k<<<512, 512, 0, stream>>>(qb, kp, vpt, hb);
    gemm_k<false,false,true,false,false><<<ggrid, 256, 0, stream>>>(hb, tWo1, bo1, x1, x2, NROW, 512);

    // phase 4: cross-attention; x3 = x2 + attn(q=x2, kv=en) @ Wo2
    ln_k<true><<<4096, 256, 0, stream>>>(en_out, g2, be2, en);
    gemm_k<true,false,false,true,false><<<ggrid, 256, 0, stream>>>(x2, tWq2, bq2, nullptr, qb, NROW, 512);
    gemm_k<false,false,false,true,true ><<<ggrid, 256, 0, stream>>>(en, tWk2, bk2, nullptr, kp, NROW, 512);
    gemm_k<false,false,false,true,false><<<ggrid, 256, 0, stream>>>(en, tWv2, bv2, nullptr, vb, NROW, 512);
    pool_k12_k<<<24576, 256, 0, stream>>>(kp);
    pool_vt_k<<<vtgrid, 256, 0, stream>>>(vb, vpt);
    attn_k<<<512, 512, 0, stream>>>(qb, kp, vpt, hb);
    gemm_k<false,false,true,false,false><<<ggrid, 256, 0, stream>>>(hb, tWo2, bo2, x2, x3, NROW, 512);

    // phase 5: x4 = LN3(x3); out = x4 + relu(x4@fW1+fb1)@fW2+fb2
    ln_k<false><<<4096, 256, 0, stream>>>(x3, g3, be3, x4);
    gemm_k<true,true,false,true,false><<<ggrid, 256, 0, stream>>>(x4, tF1, fb1, nullptr, ff1, NROW, 512);
    gemm_k<false,false,true,false,false><<<ggrid, 256, 0, stream>>>(ff1, tF2, fb2, x4, (float*)d_out, NROW, 512);
}